// Round 1
// baseline (2847.230 us; speedup 1.0000x reference)
//
#include <hip/hip_runtime.h>
#include <hip/hip_bf16.h>

#define Hh 256
#define Ss 64
#define Tt 64
#define Bb 32
#define Vv 32000

typedef __attribute__((ext_vector_type(8))) __bf16 bf16x8;
typedef __attribute__((ext_vector_type(4))) float f32x4;

// ---------------------------------------------------------------------------
// P1: annProj[b,s,:] = annotations[b,s,:] @ W1[H:2H,:] + b1   (time-invariant)
// ---------------------------------------------------------------------------
__global__ __launch_bounds__(256) void annproj_kernel(
    const float* __restrict__ ann, const float* __restrict__ W1,
    const float* __restrict__ b1, float* __restrict__ annP)
{
    int row = blockIdx.x;          // b*S + s
    int tid = threadIdx.x;         // output column j
    __shared__ float sX[Hh];
    sX[tid] = ann[row * Hh + tid];
    __syncthreads();
    const float* w = W1 + Hh * Hh; // bottom half rows multiply annotations
    float acc = b1[tid];
#pragma unroll 4
    for (int i = 0; i < Hh; i++) acc = fmaf(sX[i], w[i * Hh + tid], acc);
    annP[row * Hh + tid] = acc;
}

// ---------------------------------------------------------------------------
// P2: embProj{Z,R,H}[b,t,:] = emb[tok[b,t]] @ Wi*[H:2H,:] + fused biases
//     eZ gets biz+bhz, eR gets bir+bhr, eH gets bih (bhh stays separate).
// ---------------------------------------------------------------------------
__global__ __launch_bounds__(256) void embproj_kernel(
    const int* __restrict__ toks, const float* __restrict__ emb,
    const float* __restrict__ Wiz, const float* __restrict__ Wir,
    const float* __restrict__ Wih,
    const float* __restrict__ biz, const float* __restrict__ bir,
    const float* __restrict__ bih,
    const float* __restrict__ bhz, const float* __restrict__ bhr,
    float* __restrict__ eZ, float* __restrict__ eR, float* __restrict__ eH)
{
    int row = blockIdx.x;          // b*T + t
    int tid = threadIdx.x;
    __shared__ float sX[Hh];
    sX[tid] = emb[(size_t)toks[row] * Hh + tid];
    __syncthreads();
    const float* wz = Wiz + Hh * Hh;
    const float* wr = Wir + Hh * Hh;
    const float* wh = Wih + Hh * Hh;
    float az = biz[tid] + bhz[tid];
    float ar = bir[tid] + bhr[tid];
    float ah = bih[tid];
#pragma unroll 2
    for (int i = 0; i < Hh; i++) {
        float x = sX[i];
        int o = i * Hh + tid;
        az = fmaf(x, wz[o], az);
        ar = fmaf(x, wr[o], ar);
        ah = fmaf(x, wh[o], ah);
    }
    eZ[row * Hh + tid] = az;
    eR[row * Hh + tid] = ar;
    eH[row * Hh + tid] = ah;
}

// ---------------------------------------------------------------------------
// P3: WoutT[n][k] = bf16(Wout[k][n])  — tiled transpose so the GEMM's B
//     operand is K-contiguous (same fragment load pattern as A).
// ---------------------------------------------------------------------------
__global__ __launch_bounds__(256) void transpose_wout_kernel(
    const float* __restrict__ Wout, __hip_bfloat16* __restrict__ BT)
{
    __shared__ float tile[64][65];
    int n0 = blockIdx.x * 64, k0 = blockIdx.y * 64;
    int tid = threadIdx.x;
    int c = tid & 63, rb = tid >> 6;
#pragma unroll
    for (int it = 0; it < 16; it++) {
        int kk = it * 4 + rb;
        tile[kk][c] = Wout[(size_t)(k0 + kk) * Vv + n0 + c];
    }
    __syncthreads();
#pragma unroll
    for (int it = 0; it < 16; it++) {
        int nn = it * 4 + rb;
        BT[(size_t)(n0 + nn) * Hh + k0 + c] = __float2bfloat16(tile[c][nn]);
    }
}

// ---------------------------------------------------------------------------
// K2: the sequential decoder scan. One block per batch element b; all 64
// timesteps inside the kernel, state in LDS. 256 threads = one per H column.
// LDS: annProj[b] + annotations[b] resident (pitch 257 to spread banks).
// ---------------------------------------------------------------------------
__global__ __launch_bounds__(256) void decoder_kernel(
    const float* __restrict__ ann, const float* __restrict__ h0,
    const float* __restrict__ W1, const float* __restrict__ W2,
    const float* __restrict__ b2,
    const float* __restrict__ Wiz, const float* __restrict__ Wir,
    const float* __restrict__ Wih,
    const float* __restrict__ Whz, const float* __restrict__ Whr,
    const float* __restrict__ Whh,
    const float* __restrict__ bhh,
    const float* __restrict__ annP,
    const float* __restrict__ eZ, const float* __restrict__ eR,
    const float* __restrict__ eH,
    __hip_bfloat16* __restrict__ hidBf, float* __restrict__ attOut)
{
    int b = blockIdx.x, tid = threadIdx.x;
    __shared__ float sAnnP[Ss][Hh + 1];
    __shared__ float sAnnO[Ss][Hh + 1];
    __shared__ float sH[Hh], sHP[Hh], sCtx[Hh], sW2[Hh];
    __shared__ float sAw[Ss];
    __shared__ float sRed[4][Ss];

    for (int s = 0; s < Ss; s++) {
        sAnnP[s][tid] = annP[(b * Ss + s) * Hh + tid];
        sAnnO[s][tid] = ann[(b * Ss + s) * Hh + tid];
    }
    sH[tid] = h0[b * Hh + tid];
    sW2[tid] = W2[tid];
    float bhhj = bhh[tid];
    float b2s = b2[0];
    int sb = tid & 63, qb = tid >> 6;   // score phase: lane=s, wave=k-chunk
    __syncthreads();

    for (int t = 0; t < Tt; t++) {
        // --- A: hProj[j] = sum_i h[i] * W1[i][j] (top half of W1)
        float hp = 0.f;
#pragma unroll 4
        for (int i = 0; i < Hh; i++) hp = fmaf(sH[i], W1[i * Hh + tid], hp);
        sHP[tid] = hp;
        __syncthreads();

        // --- B: u[s] = b2 + sum_j W2[j]*relu(hProj[j] + annP[s][j])
        float part = 0.f;
#pragma unroll 4
        for (int k = 0; k < 64; k++) {
            int j = qb * 64 + k;                  // wave-uniform
            float v = sHP[j] + sAnnP[sb][j];
            part = fmaf(sW2[j], fmaxf(v, 0.f), part);
        }
        sRed[qb][sb] = part;
        __syncthreads();

        // --- C: softmax over s (wave 0) + write attentions (B,S,T)
        if (tid < 64) {
            float u = b2s + sRed[0][tid] + sRed[1][tid] + sRed[2][tid] + sRed[3][tid];
            float m = u;
#pragma unroll
            for (int off = 32; off; off >>= 1) m = fmaxf(m, __shfl_xor(m, off));
            float e = __expf(u - m);
            float ssum = e;
#pragma unroll
            for (int off = 32; off; off >>= 1) ssum += __shfl_xor(ssum, off);
            float aw = e / ssum;
            sAw[tid] = aw;
            attOut[(b * Ss + tid) * Tt + t] = aw;
        }
        __syncthreads();

        // --- D: context[j] = sum_s aw[s]*ann[b][s][j]
        float ctx = 0.f;
#pragma unroll 4
        for (int s = 0; s < Ss; s++) ctx = fmaf(sAw[s], sAnnO[s][tid], ctx);
        sCtx[tid] = ctx;
        __syncthreads();

        // --- E: GRU gates. 6 fused matvec streams over i.
        int rowt = b * Tt + t;
        float accZ = eZ[rowt * Hh + tid];   // has biz+bhz + x_t@Wiz_bot
        float accR = eR[rowt * Hh + tid];
        float accH = eH[rowt * Hh + tid];   // has bih + x_t@Wih_bot
        float accHH = 0.f;
#pragma unroll 2
        for (int i = 0; i < Hh; i++) {
            float c = sCtx[i], hv = sH[i];
            int o = i * Hh + tid;
            accZ = fmaf(c, Wiz[o], fmaf(hv, Whz[o], accZ));
            accR = fmaf(c, Wir[o], fmaf(hv, Whr[o], accR));
            accH = fmaf(c, Wih[o], accH);
            accHH = fmaf(hv, Whh[o], accHH);
        }
        float z = 1.f / (1.f + __expf(-accZ));
        float r = 1.f / (1.f + __expf(-accR));
        float g = tanhf(accH + r * (accHH + bhhj));
        float hprev = sH[tid];
        float hnew = (1.f - z) * g + z * hprev;
        __syncthreads();
        sH[tid] = hnew;
        hidBf[rowt * Hh + tid] = __float2bfloat16(hnew);
        __syncthreads();
    }
}

// ---------------------------------------------------------------------------
// K3: output = hiddens(bf16) @ WoutT^T(bf16) + bout, fp32 out.
// M=2048, N=32000, K=256. 128x128 block tile, 4 waves in 2x2, each wave
// 64x64 = 4x4 frags of mfma_f32_16x16x32_bf16. Fragments loaded directly
// from global (both operands K-contiguous; A is 1MB, L2-resident).
// ---------------------------------------------------------------------------
__global__ __launch_bounds__(256) void out_gemm_kernel(
    const __hip_bfloat16* __restrict__ A,   // (2048,256)
    const __hip_bfloat16* __restrict__ BT,  // (32000,256)
    const float* __restrict__ bout,
    float* __restrict__ C)                  // (2048,32000)
{
    int n0 = blockIdx.x * 128, m0 = blockIdx.y * 128;
    int tid = threadIdx.x;
    int w = tid >> 6, l = tid & 63;
    int wm = (w >> 1) * 64, wn = (w & 1) * 64;
    int quad = l >> 4, l15 = l & 15;

    const __hip_bfloat16* Arow = A + (size_t)(m0 + wm + l15) * Hh + quad * 8;
    const __hip_bfloat16* Brow = BT + (size_t)(n0 + wn + l15) * Hh + quad * 8;

    f32x4 acc[4][4] = {};
#pragma unroll
    for (int kk = 0; kk < 8; kk++) {
        bf16x8 af[4], bfv[4];
#pragma unroll
        for (int mi = 0; mi < 4; mi++)
            af[mi] = *(const bf16x8*)(Arow + mi * 16 * Hh + kk * 32);
#pragma unroll
        for (int ni = 0; ni < 4; ni++)
            bfv[ni] = *(const bf16x8*)(Brow + ni * 16 * Hh + kk * 32);
#pragma unroll
        for (int mi = 0; mi < 4; mi++)
#pragma unroll
            for (int ni = 0; ni < 4; ni++)
                acc[mi][ni] = __builtin_amdgcn_mfma_f32_16x16x32_bf16(
                    af[mi], bfv[ni], acc[mi][ni], 0, 0, 0);
    }
#pragma unroll
    for (int ni = 0; ni < 4; ni++) {
        int col = n0 + wn + ni * 16 + l15;
        float bo = bout[col];
#pragma unroll
        for (int mi = 0; mi < 4; mi++) {
            int rowb = m0 + wm + mi * 16 + quad * 4;
#pragma unroll
            for (int r = 0; r < 4; r++)
                C[(size_t)(rowb + r) * Vv + col] = acc[mi][ni][r] + bo;
        }
    }
}

// ---------------------------------------------------------------------------
extern "C" void kernel_launch(void* const* d_in, const int* in_sizes, int n_in,
                              void* d_out, int out_size, void* d_ws, size_t ws_size,
                              hipStream_t stream) {
    const int*   toks = (const int*)d_in[0];
    const float* ann  = (const float*)d_in[1];
    const float* h0   = (const float*)d_in[2];
    const float* emb  = (const float*)d_in[3];
    const float* W1   = (const float*)d_in[4];
    const float* b1   = (const float*)d_in[5];
    const float* W2   = (const float*)d_in[6];
    const float* b2   = (const float*)d_in[7];
    const float* Wiz  = (const float*)d_in[8];
    const float* biz  = (const float*)d_in[9];
    const float* Wir  = (const float*)d_in[10];
    const float* bir  = (const float*)d_in[11];
    const float* Wih  = (const float*)d_in[12];
    const float* bih  = (const float*)d_in[13];
    const float* Whz  = (const float*)d_in[14];
    const float* bhz  = (const float*)d_in[15];
    const float* Whr  = (const float*)d_in[16];
    const float* bhr  = (const float*)d_in[17];
    const float* Whh  = (const float*)d_in[18];
    const float* bhh  = (const float*)d_in[19];
    const float* Wout = (const float*)d_in[20];
    const float* bout = (const float*)d_in[21];

    float* out    = (float*)d_out;
    float* attOut = out + (size_t)Bb * Tt * Vv;   // attentions after output

    float* ws   = (float*)d_ws;
    float* annP = ws;                               // 524288 f32
    float* eZ   = ws + 524288;                      // 524288 f32
    float* eR   = ws + 1048576;
    float* eH   = ws + 1572864;
    __hip_bfloat16* hidBf = (__hip_bfloat16*)(ws + 2097152);  // 524288 bf16
    __hip_bfloat16* WoutT = (__hip_bfloat16*)(ws + 2359296);  // 8192000 bf16

    annproj_kernel<<<dim3(Bb * Ss), dim3(256), 0, stream>>>(ann, W1, b1, annP);
    embproj_kernel<<<dim3(Bb * Tt), dim3(256), 0, stream>>>(
        toks, emb, Wiz, Wir, Wih, biz, bir, bih, bhz, bhr, eZ, eR, eH);
    transpose_wout_kernel<<<dim3(Vv / 64, Hh / 64), dim3(256), 0, stream>>>(Wout, WoutT);
    decoder_kernel<<<dim3(Bb), dim3(256), 0, stream>>>(
        ann, h0, W1, W2, b2, Wiz, Wir, Wih, Whz, Whr, Whh, bhh,
        annP, eZ, eR, eH, hidBf, attOut);
    out_gemm_kernel<<<dim3(Vv / 128, (Bb * Tt) / 128), dim3(256), 0, stream>>>(
        hidBf, WoutT, bout, out);
}